// Round 6
// baseline (3942.970 us; speedup 1.0000x reference)
//
#include <hip/hip_runtime.h>
#include <hip/hip_bf16.h>

#define B_ 16
#define N_ 358
#define P_ 72
#define D_ 96
#define ND_ 64
#define H_ 4
#define NH_ 4
#define HD_ 24
#define K_ 10
#define BN_ (B_*N_)     /* 5728 */
#define NN_ (N_*N_)     /* 128164 */
#define RPW_ 6          /* ceil(358/64) elements per lane in wave-per-row kernels */

__device__ __forceinline__ float gelu_f(float x){ return 0.5f*x*(1.0f+erff(x*0.7071067811865476f)); }
__device__ __forceinline__ float sigm_f(float x){ return 1.0f/(1.0f+expf(-x)); }

// ---------------------------------------------------------------------------
// Kernel 1: temporal attention + node embedding (one block per (b,n) sequence)
// 384 threads, register tile 6 rows x 3 cols (72x96/384 = 18 outputs/thread).
// VGPR tiers on gfx950 are power-of-2 (8/4/2/1 waves at 64/128/256/512): the
// only reachable improvement over 2 waves/SIMD is the <=128 tier. Persistent
// accumulators aq/ak/av/ao = 4x18 = 72; peak live (scores, unroll 1) ~115.
// __launch_bounds__(384,4) pins the 128 cap -> 4 waves/SIMD, 2 blocks/CU
// (12 waves/CU) with 42.6KB LDS/block. Round-4/5 lesson: a cap below natural
// demand spills GBs to scratch; this structure is designed to FIT the cap.
// ---------------------------------------------------------------------------
__global__ __launch_bounds__(384,4) void attn_kernel(
    const float* __restrict__ patch, const float* __restrict__ pos,
    const float* __restrict__ wq, const float* __restrict__ bq,
    const float* __restrict__ wk, const float* __restrict__ bk,
    const float* __restrict__ wv, const float* __restrict__ bv,
    const float* __restrict__ wo, const float* __restrict__ bo,
    const float* __restrict__ tng, const float* __restrict__ tnb,
    float* __restrict__ node_out, float* __restrict__ meanpr_out)
{
    __shared__ float smem[10656];   // union pool (42.6KB)
    __shared__ float rr[P_];
    __shared__ float nb[D_];
    __shared__ float st2[2];

    float* const xs  = smem;            // 72*97 = 6984   (phase 1)
    float* const qh  = smem;            // 72*25 = 1800   (phase 2, per head)
    float* const kh  = smem + 1800;     // 72*25          (also holds O after PV)
    float* const vh  = smem + 3600;     // 72*25
    float* const att = smem + 5400;     // 72*73 = 5256
    float* const ats = smem;            // 72*97          (epilogue attended)

    const int tid = threadIdx.x;
    const int tc  = tid & 31;
    const int tr  = tid >> 5;           // 0..11
    const int rbase = tr * 6;
    const int bn  = blockIdx.x;
    const float* pr = patch + (size_t)bn * (P_*D_);

    // mean over P of pr (node_f) -- kept in a register by threads tid<96
    float mpr = 0.f;
    if (tid < D_) {
        for (int p = 0; p < P_; ++p) mpr += pr[p*D_+tid];
        mpr *= (1.0f/P_);
        meanpr_out[(size_t)bn*D_ + tid] = mpr;
    }

    // load X = pr + pos into LDS (stride 97); 6912/384 = 18 iterations
    for (int e = tid; e < P_*D_; e += 384) {
        int row = e / D_, col = e - row*D_;
        xs[row*97 + col] = pr[e] + pos[e];
    }
    __syncthreads();

    // ---- phase 1a: Q,K = X @ Wq/Wk + b (36 accumulators) ----
    float aq[3][6], ak[3][6];
    #pragma unroll
    for (int j = 0; j < 3; ++j) {
        const int c = tc + 32*j;
        const float vbq = bq[c], vbk = bk[c];
        #pragma unroll
        for (int i = 0; i < 6; ++i) { aq[j][i]=vbq; ak[j][i]=vbk; }
    }
    #pragma unroll 2
    for (int k = 0; k < D_; ++k) {
        float xv[6];
        #pragma unroll
        for (int i = 0; i < 6; ++i) xv[i] = xs[(rbase+i)*97 + k];
        const float* wqp = wq + k*D_;
        const float* wkp = wk + k*D_;
        float wqv[3], wkv[3];
        #pragma unroll
        for (int j = 0; j < 3; ++j) {
            const int c = tc + 32*j;
            wqv[j]=wqp[c]; wkv[j]=wkp[c];
        }
        #pragma unroll
        for (int j = 0; j < 3; ++j)
            #pragma unroll
            for (int i = 0; i < 6; ++i) {
                aq[j][i] += xv[i]*wqv[j];
                ak[j][i] += xv[i]*wkv[j];
            }
    }
    // ---- phase 1b: V = X @ Wv + b (18 accumulators) ----
    float av[3][6];
    #pragma unroll
    for (int j = 0; j < 3; ++j) {
        const float vbv = bv[tc + 32*j];
        #pragma unroll
        for (int i = 0; i < 6; ++i) av[j][i] = vbv;
    }
    #pragma unroll 2
    for (int k = 0; k < D_; ++k) {
        float xv[6];
        #pragma unroll
        for (int i = 0; i < 6; ++i) xv[i] = xs[(rbase+i)*97 + k];
        const float* wvp = wv + k*D_;
        float wvv[3];
        #pragma unroll
        for (int j = 0; j < 3; ++j) wvv[j] = wvp[tc + 32*j];
        #pragma unroll
        for (int j = 0; j < 3; ++j)
            #pragma unroll
            for (int i = 0; i < 6; ++i) av[j][i] += xv[i]*wvv[j];
    }
    __syncthreads();        // X dead; smem free for per-head buffers

    // attended accumulators (output of o @ wo + bo), live across heads
    float ao[3][6];
    #pragma unroll
    for (int j = 0; j < 3; ++j) {
        const float vbo = bo[tc + 32*j];
        #pragma unroll
        for (int i = 0; i < 6; ++i) ao[j][i] = vbo;
    }

    const float rs = 0.20412414523193154f;      // 1/sqrt(24)
    for (int h = 0; h < NH_; ++h) {
        // stage head-h slices of Q,K,V from registers into LDS
        #pragma unroll
        for (int j = 0; j < 3; ++j) {
            const int c = tc + 32*j;
            const int dl = c - HD_*h;
            if ((unsigned)dl < (unsigned)HD_) {
                #pragma unroll
                for (int i = 0; i < 6; ++i) {
                    qh[(rbase+i)*25 + dl] = aq[j][i];
                    kh[(rbase+i)*25 + dl] = ak[j][i];
                    vh[(rbase+i)*25 + dl] = av[j][i];
                }
            }
        }
        __syncthreads();    // A: qh/kh/vh visible

        // scores S = Q K^T * rs : rows rbase..rbase+5, cols jn = tc+32*jj (<72)
        {
            float sc[3][6];
            #pragma unroll
            for (int jj = 0; jj < 3; ++jj)
                #pragma unroll
                for (int i = 0; i < 6; ++i) sc[jj][i] = 0.f;
            #pragma unroll 1
            for (int d = 0; d < HD_; ++d) {
                float qv[6];
                #pragma unroll
                for (int i = 0; i < 6; ++i) qv[i] = qh[(rbase+i)*25 + d];
                float kv[3];
                #pragma unroll
                for (int jj = 0; jj < 3; ++jj) {
                    const int jn = tc + 32*jj;
                    kv[jj] = (jn < P_) ? kh[jn*25 + d] : 0.f;
                }
                #pragma unroll
                for (int jj = 0; jj < 3; ++jj)
                    #pragma unroll
                    for (int i = 0; i < 6; ++i) sc[jj][i] += qv[i]*kv[jj];
            }
            #pragma unroll
            for (int jj = 0; jj < 3; ++jj) {
                const int jn = tc + 32*jj;
                if (jn < P_) {
                    #pragma unroll
                    for (int i = 0; i < 6; ++i)
                        att[(rbase+i)*73 + jn] = sc[jj][i]*rs;
                }
            }
        }
        __syncthreads();    // B: att visible; kh reads done

        // row softmax (one thread per row)
        if (tid < P_) {
            float* ar = att + tid*73;
            float mx = ar[0];
            for (int j = 1; j < P_; ++j) mx = fmaxf(mx, ar[j]);
            float sm = 0.f;
            for (int j = 0; j < P_; ++j) { float ev = expf(ar[j]-mx); ar[j]=ev; sm += ev; }
            float inv = 1.0f/sm;
            for (int j = 0; j < P_; ++j) ar[j] *= inv;
        }
        __syncthreads();    // C

        // PV: O[i][dl] = sum_j P[i][j] V[j][dl]; O overwrites kh (dead)
        if (tc < HD_) {
            float ov[6];
            #pragma unroll
            for (int i = 0; i < 6; ++i) ov[i] = 0.f;
            #pragma unroll 2
            for (int j = 0; j < P_; ++j) {
                const float vv = vh[j*25 + tc];
                #pragma unroll
                for (int i = 0; i < 6; ++i) ov[i] += att[(rbase+i)*73 + j]*vv;
            }
            #pragma unroll
            for (int i = 0; i < 6; ++i) kh[(rbase+i)*25 + tc] = ov[i];
        }
        __syncthreads();    // D: O visible

        // Oproj: attended += O @ wo[24h:24h+24, :]
        #pragma unroll 1
        for (int d = 0; d < HD_; ++d) {
            float ovv[6];
            #pragma unroll
            for (int i = 0; i < 6; ++i) ovv[i] = kh[(rbase+i)*25 + d];
            const float* wop = wo + (HD_*h + d)*D_;
            float wv3[3];
            #pragma unroll
            for (int j = 0; j < 3; ++j) wv3[j] = wop[tc + 32*j];
            #pragma unroll
            for (int j = 0; j < 3; ++j)
                #pragma unroll
                for (int i = 0; i < 6; ++i) ao[j][i] += ovv[i]*wv3[j];
        }
        __syncthreads();    // E: O reads done before next head overwrites kh
    }

    // ---- epilogue: attended -> LDS (stride 97), imp softmax, node, LN ----
    #pragma unroll
    for (int j = 0; j < 3; ++j) {
        const int c = tc + 32*j;
        #pragma unroll
        for (int i = 0; i < 6; ++i) ats[(rbase+i)*97 + c] = ao[j][i];
    }
    __syncthreads();

    if (tid < P_) {                         // row mean over D
        const float* ar = ats + tid*97;
        float s = 0.f;
        for (int d = 0; d < D_; ++d) s += ar[d];
        rr[tid] = s*(1.0f/D_);
    }
    __syncthreads();
    if (tid == 0) {                         // imp = softmax over P
        float mx = rr[0];
        for (int i=1;i<P_;++i) mx = fmaxf(mx, rr[i]);
        float sm=0.f;
        for (int i=0;i<P_;++i){ float ev=expf(rr[i]-mx); rr[i]=ev; sm+=ev; }
        float inv=1.0f/sm;
        for (int i=0;i<P_;++i) rr[i]*=inv;
    }
    __syncthreads();
    if (tid < D_) {
        float s = 0.f;
        for (int i=0;i<P_;++i) s += ats[i*97+tid]*rr[i];
        nb[tid] = s + mpr;
    }
    __syncthreads();
    if (tid == 0) {
        float m=0.f; for(int d=0;d<D_;++d) m+=nb[d]; m *= (1.0f/D_);
        float v=0.f; for(int d=0;d<D_;++d){ float df=nb[d]-m; v+=df*df; } v *= (1.0f/D_);
        st2[0]=m; st2[1]=rsqrtf(v+1e-5f);
    }
    __syncthreads();
    if (tid < D_) {
        float y = (nb[tid]-st2[0])*st2[1]*tng[tid] + tnb[tid];
        node_out[(size_t)bn*D_+tid] = y;
    }
}

// ---------------------------------------------------------------------------
// Kernel 2: h1 = gelu(LN(node @ de_w1 + b1))
// ---------------------------------------------------------------------------
__global__ __launch_bounds__(128) void enc1_kernel(
    const float* __restrict__ node, const float* __restrict__ w1, const float* __restrict__ b1,
    const float* __restrict__ g1, const float* __restrict__ be1, float* __restrict__ h1)
{
    __shared__ float nr[D_];
    __shared__ float buf[128];
    __shared__ float st2[2];
    const int tid = threadIdx.x; const int bn = blockIdx.x;
    if (tid < D_) nr[tid] = node[(size_t)bn*D_+tid];
    __syncthreads();
    float s = b1[tid];
    for (int c = 0; c < D_; ++c) s += nr[c]*w1[c*128+tid];
    buf[tid] = s;
    __syncthreads();
    if (tid == 0) {
        float m=0.f; for(int d=0;d<128;++d) m+=buf[d]; m *= (1.0f/128.0f);
        float v=0.f; for(int d=0;d<128;++d){ float df=buf[d]-m; v+=df*df; } v *= (1.0f/128.0f);
        st2[0]=m; st2[1]=rsqrtf(v+1e-5f);
    }
    __syncthreads();
    float y = (buf[tid]-st2[0])*st2[1]*g1[tid] + be1[tid];
    h1[(size_t)bn*128+tid] = gelu_f(y);
}

// ---------------------------------------------------------------------------
// Kernel 3: dyn = LN(h1 @ de_w2 + b2)
// ---------------------------------------------------------------------------
__global__ __launch_bounds__(64) void enc2_kernel(
    const float* __restrict__ h1, const float* __restrict__ w2, const float* __restrict__ b2,
    const float* __restrict__ g2, const float* __restrict__ be2, float* __restrict__ dyn)
{
    __shared__ float hr[128];
    __shared__ float buf[ND_];
    __shared__ float st2[2];
    const int tid = threadIdx.x; const int bn = blockIdx.x;
    hr[tid] = h1[(size_t)bn*128+tid];
    hr[tid+64] = h1[(size_t)bn*128+64+tid];
    __syncthreads();
    float s = b2[tid];
    for (int c = 0; c < 128; ++c) s += hr[c]*w2[c*ND_+tid];
    buf[tid] = s;
    __syncthreads();
    if (tid == 0) {
        float m=0.f; for(int d=0;d<ND_;++d) m+=buf[d]; m *= (1.0f/ND_);
        float v=0.f; for(int d=0;d<ND_;++d){ float df=buf[d]-m; v+=df*df; } v *= (1.0f/ND_);
        st2[0]=m; st2[1]=rsqrtf(v+1e-5f);
    }
    __syncthreads();
    dyn[(size_t)bn*ND_+tid] = (buf[tid]-st2[0])*st2[1]*g2[tid] + be2[tid];
}

// ---------------------------------------------------------------------------
// Kernel 4: one GNN layer (one block per (b,n) row)
// ---------------------------------------------------------------------------
__global__ __launch_bounds__(256) void gnn_kernel(
    const float* __restrict__ din, float* __restrict__ dout,
    const float* __restrict__ gw, const float* __restrict__ gb,
    const float* __restrict__ gg, const float* __restrict__ gbe, int layer)
{
    __shared__ float dq[ND_];
    __shared__ float prob[N_];
    __shared__ float red[256];
    __shared__ float aggp[4*ND_];
    __shared__ float buf[ND_];
    __shared__ float st2[2];
    const int tid = threadIdx.x; const int bn = blockIdx.x;
    const int b = bn / N_;
    const float* base = din + (size_t)b*N_*ND_;
    if (tid < ND_) dq[tid] = din[(size_t)bn*ND_+tid];
    __syncthreads();

    float lmax = -1e30f;
    for (int m = tid; m < N_; m += 256) {
        const float* rm = base + (size_t)m*ND_;
        float s = 0.f;
        for (int c = 0; c < ND_; ++c) s += dq[c]*rm[c];
        s *= 5.0f;                              // /0.2
        prob[m] = s;
        lmax = fmaxf(lmax, s);
    }
    red[tid]=lmax; __syncthreads();
    for (int st=128; st>0; st>>=1){ if(tid<st) red[tid]=fmaxf(red[tid],red[tid+st]); __syncthreads(); }
    const float mx = red[0]; __syncthreads();
    float lsum = 0.f;
    for (int m=tid; m<N_; m+=256){ float ev=expf(prob[m]-mx); prob[m]=ev; lsum+=ev; }
    red[tid]=lsum; __syncthreads();
    for (int st=128; st>0; st>>=1){ if(tid<st) red[tid]+=red[tid+st]; __syncthreads(); }
    const float inv = 1.0f/red[0]; __syncthreads();
    for (int m=tid; m<N_; m+=256) prob[m]*=inv;
    __syncthreads();

    {   // agg = sim @ dyn
        const int part = tid >> 6, d = tid & 63;
        float s = 0.f;
        for (int m = part; m < N_; m += 4) s += prob[m]*base[(size_t)m*ND_+d];
        aggp[part*ND_+d] = s;
    }
    __syncthreads();
    if (tid < ND_)
        aggp[tid] = aggp[tid]+aggp[ND_+tid]+aggp[2*ND_+tid]+aggp[3*ND_+tid];
    __syncthreads();
    if (tid < ND_) {
        float t = gb[layer*ND_+tid];
        for (int c = 0; c < ND_; ++c) t += aggp[c]*gw[(layer*ND_+c)*ND_+tid];
        buf[tid] = t;
    }
    __syncthreads();
    if (tid == 0) {
        float m=0.f; for(int d=0;d<ND_;++d) m+=buf[d]; m *= (1.0f/ND_);
        float v=0.f; for(int d=0;d<ND_;++d){ float df=buf[d]-m; v+=df*df; } v *= (1.0f/ND_);
        st2[0]=m; st2[1]=rsqrtf(v+1e-5f);
    }
    __syncthreads();
    if (tid < ND_) {
        float y = (buf[tid]-st2[0])*st2[1]*gg[layer*ND_+tid] + gbe[layer*ND_+tid];
        dout[(size_t)bn*ND_+tid] = gelu_f(y) + dq[tid];
    }
}

// ---------------------------------------------------------------------------
// Wave-per-row softmax + top-k + renormalize + store. No __syncthreads.
// lv[j] = relu'd, temperature-scaled logits at positions m = lane + 64*j.
// Tie-break: max value, lowest index (matches lax.top_k stability).
// ---------------------------------------------------------------------------
__device__ __forceinline__ void wave_softmax_topk_store(
    float lv[RPW_], int lane, float* __restrict__ outrow)
{
    float mx = 0.f;                     // logits >= 0 (post-relu), 0 is a valid floor
    #pragma unroll
    for (int j=0;j<RPW_;++j) mx = fmaxf(mx, lv[j]);
    #pragma unroll
    for (int s=1;s<64;s<<=1) mx = fmaxf(mx, __shfl_xor(mx, s));
    float sm = 0.f;
    #pragma unroll
    for (int j=0;j<RPW_;++j) {
        const int m = lane + 64*j;
        const float e = (m < N_) ? expf(lv[j]-mx) : 0.f;
        lv[j] = e; sm += e;
    }
    #pragma unroll
    for (int s=1;s<64;s<<=1) sm += __shfl_xor(sm, s);
    const float inv = 1.0f/sm;
    #pragma unroll
    for (int j=0;j<RPW_;++j) lv[j] *= inv;

    unsigned sel = 0u;
    float ksum = 0.f;
    for (int it = 0; it < K_; ++it) {
        float bv = -1.f; int bm = 0x7fffffff;
        #pragma unroll
        for (int j=0;j<RPW_;++j) {
            const int m = lane + 64*j;
            if (m < N_ && !((sel>>j)&1u) && lv[j] > bv) { bv = lv[j]; bm = m; }
        }
        #pragma unroll
        for (int s=1;s<64;s<<=1) {
            const float ov = __shfl_xor(bv, s);
            const int   om = __shfl_xor(bm, s);
            if (ov > bv || (ov == bv && om < bm)) { bv = ov; bm = om; }
        }
        ksum += bv;
        if ((bm & 63) == lane) sel |= 1u << (bm >> 6);
    }
    const float dn = 1.0f/(ksum + 1e-8f);
    #pragma unroll
    for (int j=0;j<RPW_;++j) {
        const int m = lane + 64*j;
        if (m < N_) outrow[m] = ((sel>>j)&1u) ? lv[j]*dn : 0.f;
    }
}

// ---------------------------------------------------------------------------
// Kernel 5: static adjacency — one WAVE per (h,n) row; 4 rows per block
// ---------------------------------------------------------------------------
__global__ __launch_bounds__(256) void static_adj_kernel(
    const float* __restrict__ le1, const float* __restrict__ le2,
    const float* __restrict__ ge1, const float* __restrict__ ge2,
    const float* __restrict__ temp, float* __restrict__ outs)
{
    __shared__ float e1l[4][ND_];
    const int tid = threadIdx.x;
    const int wv = tid >> 6, lane = tid & 63;
    const int r = blockIdx.x*4 + wv;        // r = h*N_ + n, grid = H_*N_/4
    const int h = r / N_, n = r % N_;
    if (h < 2) { if (lane < 32) e1l[wv][lane] = le1[(h*N_+n)*32+lane]; }
    else       { e1l[wv][lane] = ge1[((h-2)*N_+n)*64+lane]; }
    __syncthreads();
    const float t = temp[h];
    const float tl = (h < 2) ? fminf(fmaxf(t*2.0f,0.1f),5.0f) : fminf(fmaxf(t*0.5f,0.1f),2.0f);
    const float invt = 1.0f/tl;
    float lv[RPW_];
    #pragma unroll
    for (int j=0;j<RPW_;++j) lv[j] = 0.f;
    if (h < 2) {
        for (int c = 0; c < 32; ++c) {
            const float dc = e1l[wv][c];
            const float* sr = le2 + (size_t)(h*32+c)*N_;
            #pragma unroll
            for (int j=0;j<RPW_;++j) {
                const int m = lane + 64*j;
                if (m < N_) lv[j] += dc*sr[m];
            }
        }
    } else {
        for (int c = 0; c < 64; ++c) {
            const float dc = e1l[wv][c];
            const float* sr = ge2 + (size_t)((h-2)*64+c)*N_;
            #pragma unroll
            for (int j=0;j<RPW_;++j) {
                const int m = lane + 64*j;
                if (m < N_) lv[j] += dc*sr[m];
            }
        }
    }
    #pragma unroll
    for (int j=0;j<RPW_;++j) lv[j] = fmaxf(lv[j],0.f)*invt;
    wave_softmax_topk_store(lv, lane, outs + (size_t)r*N_);
}

// ---------------------------------------------------------------------------
// Kernel 6: dynamic adjacency — one WAVE per (b,h,n) row; 4 rows per block
// ---------------------------------------------------------------------------
__global__ __launch_bounds__(256) void dyn_adj_kernel(
    const float* __restrict__ dyn, const float* __restrict__ se2,
    const float* __restrict__ temp, float* __restrict__ outd)
{
    __shared__ float dql[4][ND_];
    const int tid = threadIdx.x;
    const int wv = tid >> 6, lane = tid & 63;
    const int r = blockIdx.x*4 + wv;        // grid = B_*H_*N_/4 = 5728
    const int b = r / (H_*N_);
    const int rem = r % (H_*N_);
    const int h = rem / N_, n = rem % N_;
    dql[wv][lane] = dyn[((size_t)(b*N_+n))*ND_ + lane];
    __syncthreads();
    const float invt = 1.0f/fminf(fmaxf(temp[h],0.1f),2.0f);
    float lv[RPW_];
    #pragma unroll
    for (int j=0;j<RPW_;++j) lv[j] = 0.f;
    const float* sb = se2 + (size_t)h*ND_*N_;
    for (int c = 0; c < ND_; ++c) {
        const float dc = dql[wv][c];
        const float* sr = sb + (size_t)c*N_;
        #pragma unroll
        for (int j=0;j<RPW_;++j) {
            const int m = lane + 64*j;
            if (m < N_) lv[j] += dc*sr[m];
        }
    }
    #pragma unroll
    for (int j=0;j<RPW_;++j) lv[j] = fmaxf(lv[j],0.f)*invt;
    wave_softmax_topk_store(lv, lane, outd + ((size_t)(b*H_+h)*N_+n)*(size_t)N_);
}

// ---------------------------------------------------------------------------
// Kernel 7: fusion gate  w = sigmoid(node_f @ gf_w + gf_b)
// ---------------------------------------------------------------------------
__global__ __launch_bounds__(256) void fw_kernel(
    const float* __restrict__ meanpr, const float* __restrict__ gfw,
    const float* __restrict__ gfb, float* __restrict__ wf)
{
    const int gid = blockIdx.x*256 + threadIdx.x;
    if (gid >= BN_*H_) return;
    const int bn = gid >> 2, h = gid & 3;
    float s = gfb[h];
    const float* mp = meanpr + (size_t)bn*D_;
    for (int c=0;c<D_;++c) s += mp[c]*gfw[c*H_+h];
    wf[gid] = sigm_f(s);
}

// ---------------------------------------------------------------------------
// Kernel 8: fusion + edge-encoder MLP + final (one thread per (b,n,m))
// ---------------------------------------------------------------------------
__global__ __launch_bounds__(256) void edge_kernel(
    const float* __restrict__ staticf, const float* __restrict__ dynf,
    const float* __restrict__ wf,
    const float* __restrict__ ew1, const float* __restrict__ eb1,
    const float* __restrict__ eg,  const float* __restrict__ ebe,
    const float* __restrict__ ew2, const float* __restrict__ eb2,
    const float* __restrict__ ew3, const float* __restrict__ eb3,
    float* __restrict__ outf)
{
    __shared__ float w1s[64], w2s[128], b1s[16], gs[16], bes[16], b2s[8], w3s[8];
    __shared__ float b3v;
    const int tid = threadIdx.x;
    if (tid < 64)                 w1s[tid]     = ew1[tid];
    else if (tid < 192)           w2s[tid-64]  = ew2[tid-64];
    else if (tid < 208)           b1s[tid-192] = eb1[tid-192];
    else if (tid < 224)           gs[tid-208]  = eg[tid-208];
    else if (tid < 240)           bes[tid-224] = ebe[tid-224];
    else if (tid < 248)           b2s[tid-240] = eb2[tid-240];
    else                          w3s[tid-248] = ew3[tid-248];
    if (tid == 0) b3v = eb3[0];
    __syncthreads();

    const size_t gid = (size_t)blockIdx.x*256 + tid;
    if (gid >= (size_t)B_*NN_) return;
    const int m = (int)(gid % N_);
    const size_t t1 = gid / N_;
    const int n = (int)(t1 % N_);
    const int b = (int)(t1 / N_);

    const float* wrow = wf + ((size_t)(b*N_+n))*4;
    float mh[4]; float msum = 0.f;
    #pragma unroll
    for (int h=0; h<4; ++h) {
        float w  = wrow[h];
        float st = staticf[((size_t)(h*N_+n))*N_ + m];
        float da = dynf[(((size_t)(b*4+h))*N_+n)*(size_t)N_ + m];
        float f = (1.0f-w)*st + w*da;
        mh[h] = f; msum += f;
    }
    float e16[16]; float mean = 0.f;
    #pragma unroll
    for (int j=0;j<16;++j) {
        float s = b1s[j];
        #pragma unroll
        for (int h=0;h<4;++h) s += mh[h]*w1s[h*16+j];
        e16[j] = s; mean += s;
    }
    mean *= (1.0f/16.0f);
    float var = 0.f;
    #pragma unroll
    for (int j=0;j<16;++j){ float df=e16[j]-mean; var += df*df; }
    var *= (1.0f/16.0f);
    const float rinv = rsqrtf(var + 1e-5f);
    #pragma unroll
    for (int j=0;j<16;++j) e16[j] = gelu_f((e16[j]-mean)*rinv*gs[j] + bes[j]);
    float e8[8];
    #pragma unroll
    for (int o=0;o<8;++o) {
        float s = b2s[o];
        #pragma unroll
        for (int j=0;j<16;++j) s += e16[j]*w2s[j*8+o];
        e8[o] = gelu_f(s);
    }
    float e = b3v;
    #pragma unroll
    for (int o=0;o<8;++o) e += e8[o]*w3s[o];
    outf[gid] = sigm_f(e) * (msum*0.25f);
}

// ---------------------------------------------------------------------------
extern "C" void kernel_launch(void* const* d_in, const int* in_sizes, int n_in,
                              void* d_out, int out_size, void* d_ws, size_t ws_size,
                              hipStream_t stream)
{
    const float* patch = (const float*)d_in[0];
    const float* le1   = (const float*)d_in[1];
    const float* le2   = (const float*)d_in[2];
    const float* ge1   = (const float*)d_in[3];
    const float* ge2   = (const float*)d_in[4];
    const float* se2   = (const float*)d_in[5];
    const float* temp  = (const float*)d_in[6];
    const float* pos   = (const float*)d_in[7];
    const float* wq    = (const float*)d_in[8];
    const float* bq    = (const float*)d_in[9];
    const float* wk    = (const float*)d_in[10];
    const float* bk    = (const float*)d_in[11];
    const float* wv    = (const float*)d_in[12];
    const float* bv    = (const float*)d_in[13];
    const float* wo    = (const float*)d_in[14];
    const float* bo    = (const float*)d_in[15];
    const float* tng   = (const float*)d_in[16];
    const float* tnb   = (const float*)d_in[17];
    const float* dw1   = (const float*)d_in[18];
    const float* db1   = (const float*)d_in[19];
    const float* dg1   = (const float*)d_in[20];
    const float* dbe1  = (const float*)d_in[21];
    const float* dw2   = (const float*)d_in[22];
    const float* db2   = (const float*)d_in[23];
    const float* dg2   = (const float*)d_in[24];
    const float* dbe2  = (const float*)d_in[25];
    const float* gw    = (const float*)d_in[26];
    const float* gb    = (const float*)d_in[27];
    const float* gg    = (const float*)d_in[28];
    const float* gbe   = (const float*)d_in[29];
    const float* gfw   = (const float*)d_in[30];
    const float* gfb   = (const float*)d_in[31];
    const float* ew1   = (const float*)d_in[32];
    const float* eb1   = (const float*)d_in[33];
    const float* eg    = (const float*)d_in[34];
    const float* ebe   = (const float*)d_in[35];
    const float* ew2   = (const float*)d_in[36];
    const float* eb2   = (const float*)d_in[37];
    const float* ew3   = (const float*)d_in[38];
    const float* eb3   = (const float*)d_in[39];
    (void)in_sizes; (void)n_in; (void)out_size; (void)ws_size;

    // workspace layout (with aliasing of dead buffers): BN*384 floats = 8.8 MB
    float* ws      = (float*)d_ws;
    float* meanpr  = ws;                        // BN*96, live until fw_kernel
    float* node    = meanpr + (size_t)BN_*D_;   // BN*96; dead after enc1 -> reused as dyn1
    float* h1      = node   + (size_t)BN_*D_;   // BN*128; dead after enc2 -> reused as wfuse
    float* dyn0    = h1     + (size_t)BN_*128;  // BN*64
    float* dyn1    = node;                      // alias (gnn layer0 output)
    float* wfuse   = h1;                        // alias (BN*4)

    float* out        = (float*)d_out;
    float* out_final  = out;
    float* out_static = out + (size_t)B_*NN_;
    float* out_dyn    = out_static + (size_t)H_*NN_;

    attn_kernel<<<BN_, 384, 0, stream>>>(patch,pos,wq,bq,wk,bk,wv,bv,wo,bo,tng,tnb,node,meanpr);
    enc1_kernel<<<BN_, 128, 0, stream>>>(node,dw1,db1,dg1,dbe1,h1);
    enc2_kernel<<<BN_, 64,  0, stream>>>(h1,dw2,db2,dg2,dbe2,dyn0);
    gnn_kernel<<<BN_, 256, 0, stream>>>(dyn0,dyn1,gw,gb,gg,gbe,0);
    gnn_kernel<<<BN_, 256, 0, stream>>>(dyn1,dyn0,gw,gb,gg,gbe,1);
    static_adj_kernel<<<H_*N_/4, 256, 0, stream>>>(le1,le2,ge1,ge2,temp,out_static);
    dyn_adj_kernel<<<B_*H_*N_/4, 256, 0, stream>>>(dyn0,se2,temp,out_dyn);
    fw_kernel<<<(BN_*H_+255)/256, 256, 0, stream>>>(meanpr,gfw,gfb,wfuse);
    edge_kernel<<<((size_t)B_*NN_+255)/256, 256, 0, stream>>>(
        out_static,out_dyn,wfuse,ew1,eb1,eg,ebe,ew2,eb2,ew3,eb3,out_final);
}

// Round 7
// 2866.400 us; speedup vs baseline: 1.3756x; 1.3756x over previous
//
#include <hip/hip_runtime.h>
#include <hip/hip_bf16.h>

#define B_ 16
#define N_ 358
#define P_ 72
#define D_ 96
#define ND_ 64
#define H_ 4
#define NH_ 4
#define HD_ 24
#define K_ 10
#define BN_ (B_*N_)     /* 5728 */
#define NN_ (N_*N_)     /* 128164 */
#define RPW_ 6          /* ceil(358/64) elements per lane in wave-per-row kernels */

__device__ __forceinline__ float gelu_f(float x){ return 0.5f*x*(1.0f+erff(x*0.7071067811865476f)); }
__device__ __forceinline__ float sigm_f(float x){ return 1.0f/(1.0f+expf(-x)); }

// ---------------------------------------------------------------------------
// Kernel 1: temporal attention + node embedding (one block per (b,n) sequence)
// ROUND-3 PROVEN CONFIG: 256 threads, 9x3 register tiles, NATURAL register
// allocation (248 VGPR, zero spill). Do NOT add a waves-per-EU bound or
// unroll caps: R4 (256,3)->spill 12.9GB; R5 pragmas+(256,3)->spill 2.3GB;
// R6 (384,4)->compiler picked 64-VGPR tier, spill 1.4GB. Natural 248 = 2
// waves/SIMD is the stable zero-spill operating point (VGPR tiers are
// power-of-2: 129..256 all give 2 waves/SIMD).
// ---------------------------------------------------------------------------
__global__ __launch_bounds__(256) void attn_kernel(
    const float* __restrict__ patch, const float* __restrict__ pos,
    const float* __restrict__ wq, const float* __restrict__ bq,
    const float* __restrict__ wk, const float* __restrict__ bk,
    const float* __restrict__ wv, const float* __restrict__ bv,
    const float* __restrict__ wo, const float* __restrict__ bo,
    const float* __restrict__ tng, const float* __restrict__ tnb,
    float* __restrict__ node_out, float* __restrict__ meanpr_out)
{
    __shared__ float smem[10656];   // union pool (42.6KB)
    __shared__ float rr[P_];
    __shared__ float nb[D_];
    __shared__ float st2[2];

    float* const xs  = smem;            // 72*97 = 6984   (phase 1)
    float* const qh  = smem;            // 72*25 = 1800   (phase 2, per head)
    float* const kh  = smem + 1800;     // 72*25          (also holds O after PV)
    float* const vh  = smem + 3600;     // 72*25
    float* const att = smem + 5400;     // 72*73 = 5256
    float* const ats = smem;            // 72*97          (epilogue attended)

    const int tid = threadIdx.x;
    const int tc  = tid & 31;
    const int tr  = tid >> 5;           // 0..7
    const int rbase = tr * 9;
    const int bn  = blockIdx.x;
    const float* pr = patch + (size_t)bn * (P_*D_);

    // mean over P of pr (node_f) -- kept in a register by threads tid<96
    float mpr = 0.f;
    if (tid < D_) {
        for (int p = 0; p < P_; ++p) mpr += pr[p*D_+tid];
        mpr *= (1.0f/P_);
        meanpr_out[(size_t)bn*D_ + tid] = mpr;
    }

    // load X = pr + pos into LDS (stride 97)
    for (int e = tid; e < P_*D_; e += 256) {
        int row = e / D_, col = e - row*D_;
        xs[row*97 + col] = pr[e] + pos[e];
    }
    __syncthreads();

    // ---- phase 1: Q,K,V = X @ W + b, all heads, accumulated in registers ----
    float aq[3][9], ak[3][9], av[3][9];
    #pragma unroll
    for (int j = 0; j < 3; ++j) {
        const int c = tc + 32*j;
        const float vbq = bq[c], vbk = bk[c], vbv = bv[c];
        #pragma unroll
        for (int i = 0; i < 9; ++i) { aq[j][i]=vbq; ak[j][i]=vbk; av[j][i]=vbv; }
    }
    for (int k = 0; k < D_; ++k) {
        float xv[9];
        #pragma unroll
        for (int i = 0; i < 9; ++i) xv[i] = xs[(rbase+i)*97 + k];
        const float* wqp = wq + k*D_;
        const float* wkp = wk + k*D_;
        const float* wvp = wv + k*D_;
        float wqv[3], wkv[3], wvv[3];
        #pragma unroll
        for (int j = 0; j < 3; ++j) {
            const int c = tc + 32*j;
            wqv[j]=wqp[c]; wkv[j]=wkp[c]; wvv[j]=wvp[c];
        }
        #pragma unroll
        for (int j = 0; j < 3; ++j)
            #pragma unroll
            for (int i = 0; i < 9; ++i) {
                aq[j][i] += xv[i]*wqv[j];
                ak[j][i] += xv[i]*wkv[j];
                av[j][i] += xv[i]*wvv[j];
            }
    }
    __syncthreads();        // X dead; smem free for per-head buffers

    // attended accumulators (output of o @ wo + bo), live across heads
    float ao[3][9];
    #pragma unroll
    for (int j = 0; j < 3; ++j) {
        const float vbo = bo[tc + 32*j];
        #pragma unroll
        for (int i = 0; i < 9; ++i) ao[j][i] = vbo;
    }

    const float rs = 0.20412414523193154f;      // 1/sqrt(24)
    for (int h = 0; h < NH_; ++h) {
        // stage head-h slices of Q,K,V from registers into LDS
        #pragma unroll
        for (int j = 0; j < 3; ++j) {
            const int c = tc + 32*j;
            const int dl = c - HD_*h;
            if ((unsigned)dl < (unsigned)HD_) {
                #pragma unroll
                for (int i = 0; i < 9; ++i) {
                    qh[(rbase+i)*25 + dl] = aq[j][i];
                    kh[(rbase+i)*25 + dl] = ak[j][i];
                    vh[(rbase+i)*25 + dl] = av[j][i];
                }
            }
        }
        __syncthreads();    // A: qh/kh/vh visible

        // scores S = Q K^T * rs : rows rbase..rbase+8, cols jn = tc+32*jj (<72)
        {
            float sc[3][9];
            #pragma unroll
            for (int jj = 0; jj < 3; ++jj)
                #pragma unroll
                for (int i = 0; i < 9; ++i) sc[jj][i] = 0.f;
            for (int d = 0; d < HD_; ++d) {
                float qv[9];
                #pragma unroll
                for (int i = 0; i < 9; ++i) qv[i] = qh[(rbase+i)*25 + d];
                float kv[3];
                #pragma unroll
                for (int jj = 0; jj < 3; ++jj) {
                    const int jn = tc + 32*jj;
                    kv[jj] = (jn < P_) ? kh[jn*25 + d] : 0.f;
                }
                #pragma unroll
                for (int jj = 0; jj < 3; ++jj)
                    #pragma unroll
                    for (int i = 0; i < 9; ++i) sc[jj][i] += qv[i]*kv[jj];
            }
            #pragma unroll
            for (int jj = 0; jj < 3; ++jj) {
                const int jn = tc + 32*jj;
                if (jn < P_) {
                    #pragma unroll
                    for (int i = 0; i < 9; ++i)
                        att[(rbase+i)*73 + jn] = sc[jj][i]*rs;
                }
            }
        }
        __syncthreads();    // B: att visible; kh reads done

        // row softmax (one thread per row)
        if (tid < P_) {
            float* ar = att + tid*73;
            float mx = ar[0];
            for (int j = 1; j < P_; ++j) mx = fmaxf(mx, ar[j]);
            float sm = 0.f;
            for (int j = 0; j < P_; ++j) { float ev = expf(ar[j]-mx); ar[j]=ev; sm += ev; }
            float inv = 1.0f/sm;
            for (int j = 0; j < P_; ++j) ar[j] *= inv;
        }
        __syncthreads();    // C

        // PV: O[i][dl] = sum_j P[i][j] V[j][dl]; O overwrites kh (dead)
        if (tc < HD_) {
            float ov[9];
            #pragma unroll
            for (int i = 0; i < 9; ++i) ov[i] = 0.f;
            for (int j = 0; j < P_; ++j) {
                const float vv = vh[j*25 + tc];
                #pragma unroll
                for (int i = 0; i < 9; ++i) ov[i] += att[(rbase+i)*73 + j]*vv;
            }
            #pragma unroll
            for (int i = 0; i < 9; ++i) kh[(rbase+i)*25 + tc] = ov[i];
        }
        __syncthreads();    // D: O visible

        // Oproj: attended += O @ wo[24h:24h+24, :]
        for (int d = 0; d < HD_; ++d) {
            float ovv[9];
            #pragma unroll
            for (int i = 0; i < 9; ++i) ovv[i] = kh[(rbase+i)*25 + d];
            const float* wop = wo + (HD_*h + d)*D_;
            float wv3[3];
            #pragma unroll
            for (int j = 0; j < 3; ++j) wv3[j] = wop[tc + 32*j];
            #pragma unroll
            for (int j = 0; j < 3; ++j)
                #pragma unroll
                for (int i = 0; i < 9; ++i) ao[j][i] += ovv[i]*wv3[j];
        }
        __syncthreads();    // E: O reads done before next head overwrites kh
    }

    // ---- epilogue: attended -> LDS (stride 97), imp softmax, node, LN ----
    #pragma unroll
    for (int j = 0; j < 3; ++j) {
        const int c = tc + 32*j;
        #pragma unroll
        for (int i = 0; i < 9; ++i) ats[(rbase+i)*97 + c] = ao[j][i];
    }
    __syncthreads();

    if (tid < P_) {                         // row mean over D
        const float* ar = ats + tid*97;
        float s = 0.f;
        for (int d = 0; d < D_; ++d) s += ar[d];
        rr[tid] = s*(1.0f/D_);
    }
    __syncthreads();
    if (tid == 0) {                         // imp = softmax over P
        float mx = rr[0];
        for (int i=1;i<P_;++i) mx = fmaxf(mx, rr[i]);
        float sm=0.f;
        for (int i=0;i<P_;++i){ float ev=expf(rr[i]-mx); rr[i]=ev; sm+=ev; }
        float inv=1.0f/sm;
        for (int i=0;i<P_;++i) rr[i]*=inv;
    }
    __syncthreads();
    if (tid < D_) {
        float s = 0.f;
        for (int i=0;i<P_;++i) s += ats[i*97+tid]*rr[i];
        nb[tid] = s + mpr;
    }
    __syncthreads();
    if (tid == 0) {
        float m=0.f; for(int d=0;d<D_;++d) m+=nb[d]; m *= (1.0f/D_);
        float v=0.f; for(int d=0;d<D_;++d){ float df=nb[d]-m; v+=df*df; } v *= (1.0f/D_);
        st2[0]=m; st2[1]=rsqrtf(v+1e-5f);
    }
    __syncthreads();
    if (tid < D_) {
        float y = (nb[tid]-st2[0])*st2[1]*tng[tid] + tnb[tid];
        node_out[(size_t)bn*D_+tid] = y;
    }
}

// ---------------------------------------------------------------------------
// Kernel 2: h1 = gelu(LN(node @ de_w1 + b1))
// ---------------------------------------------------------------------------
__global__ __launch_bounds__(128) void enc1_kernel(
    const float* __restrict__ node, const float* __restrict__ w1, const float* __restrict__ b1,
    const float* __restrict__ g1, const float* __restrict__ be1, float* __restrict__ h1)
{
    __shared__ float nr[D_];
    __shared__ float buf[128];
    __shared__ float st2[2];
    const int tid = threadIdx.x; const int bn = blockIdx.x;
    if (tid < D_) nr[tid] = node[(size_t)bn*D_+tid];
    __syncthreads();
    float s = b1[tid];
    for (int c = 0; c < D_; ++c) s += nr[c]*w1[c*128+tid];
    buf[tid] = s;
    __syncthreads();
    if (tid == 0) {
        float m=0.f; for(int d=0;d<128;++d) m+=buf[d]; m *= (1.0f/128.0f);
        float v=0.f; for(int d=0;d<128;++d){ float df=buf[d]-m; v+=df*df; } v *= (1.0f/128.0f);
        st2[0]=m; st2[1]=rsqrtf(v+1e-5f);
    }
    __syncthreads();
    float y = (buf[tid]-st2[0])*st2[1]*g1[tid] + be1[tid];
    h1[(size_t)bn*128+tid] = gelu_f(y);
}

// ---------------------------------------------------------------------------
// Kernel 3: dyn = LN(h1 @ de_w2 + b2)
// ---------------------------------------------------------------------------
__global__ __launch_bounds__(64) void enc2_kernel(
    const float* __restrict__ h1, const float* __restrict__ w2, const float* __restrict__ b2,
    const float* __restrict__ g2, const float* __restrict__ be2, float* __restrict__ dyn)
{
    __shared__ float hr[128];
    __shared__ float buf[ND_];
    __shared__ float st2[2];
    const int tid = threadIdx.x; const int bn = blockIdx.x;
    hr[tid] = h1[(size_t)bn*128+tid];
    hr[tid+64] = h1[(size_t)bn*128+64+tid];
    __syncthreads();
    float s = b2[tid];
    for (int c = 0; c < 128; ++c) s += hr[c]*w2[c*ND_+tid];
    buf[tid] = s;
    __syncthreads();
    if (tid == 0) {
        float m=0.f; for(int d=0;d<ND_;++d) m+=buf[d]; m *= (1.0f/ND_);
        float v=0.f; for(int d=0;d<ND_;++d){ float df=buf[d]-m; v+=df*df; } v *= (1.0f/ND_);
        st2[0]=m; st2[1]=rsqrtf(v+1e-5f);
    }
    __syncthreads();
    dyn[(size_t)bn*ND_+tid] = (buf[tid]-st2[0])*st2[1]*g2[tid] + be2[tid];
}

// ---------------------------------------------------------------------------
// Kernel 4: one GNN layer (one block per (b,n) row)
// ---------------------------------------------------------------------------
__global__ __launch_bounds__(256) void gnn_kernel(
    const float* __restrict__ din, float* __restrict__ dout,
    const float* __restrict__ gw, const float* __restrict__ gb,
    const float* __restrict__ gg, const float* __restrict__ gbe, int layer)
{
    __shared__ float dq[ND_];
    __shared__ float prob[N_];
    __shared__ float red[256];
    __shared__ float aggp[4*ND_];
    __shared__ float buf[ND_];
    __shared__ float st2[2];
    const int tid = threadIdx.x; const int bn = blockIdx.x;
    const int b = bn / N_;
    const float* base = din + (size_t)b*N_*ND_;
    if (tid < ND_) dq[tid] = din[(size_t)bn*ND_+tid];
    __syncthreads();

    float lmax = -1e30f;
    for (int m = tid; m < N_; m += 256) {
        const float* rm = base + (size_t)m*ND_;
        float s = 0.f;
        for (int c = 0; c < ND_; ++c) s += dq[c]*rm[c];
        s *= 5.0f;                              // /0.2
        prob[m] = s;
        lmax = fmaxf(lmax, s);
    }
    red[tid]=lmax; __syncthreads();
    for (int st=128; st>0; st>>=1){ if(tid<st) red[tid]=fmaxf(red[tid],red[tid+st]); __syncthreads(); }
    const float mx = red[0]; __syncthreads();
    float lsum = 0.f;
    for (int m=tid; m<N_; m+=256){ float ev=expf(prob[m]-mx); prob[m]=ev; lsum+=ev; }
    red[tid]=lsum; __syncthreads();
    for (int st=128; st>0; st>>=1){ if(tid<st) red[tid]+=red[tid+st]; __syncthreads(); }
    const float inv = 1.0f/red[0]; __syncthreads();
    for (int m=tid; m<N_; m+=256) prob[m]*=inv;
    __syncthreads();

    {   // agg = sim @ dyn
        const int part = tid >> 6, d = tid & 63;
        float s = 0.f;
        for (int m = part; m < N_; m += 4) s += prob[m]*base[(size_t)m*ND_+d];
        aggp[part*ND_+d] = s;
    }
    __syncthreads();
    if (tid < ND_)
        aggp[tid] = aggp[tid]+aggp[ND_+tid]+aggp[2*ND_+tid]+aggp[3*ND_+tid];
    __syncthreads();
    if (tid < ND_) {
        float t = gb[layer*ND_+tid];
        for (int c = 0; c < ND_; ++c) t += aggp[c]*gw[(layer*ND_+c)*ND_+tid];
        buf[tid] = t;
    }
    __syncthreads();
    if (tid == 0) {
        float m=0.f; for(int d=0;d<ND_;++d) m+=buf[d]; m *= (1.0f/ND_);
        float v=0.f; for(int d=0;d<ND_;++d){ float df=buf[d]-m; v+=df*df; } v *= (1.0f/ND_);
        st2[0]=m; st2[1]=rsqrtf(v+1e-5f);
    }
    __syncthreads();
    if (tid < ND_) {
        float y = (buf[tid]-st2[0])*st2[1]*gg[layer*ND_+tid] + gbe[layer*ND_+tid];
        dout[(size_t)bn*ND_+tid] = gelu_f(y) + dq[tid];
    }
}

// ---------------------------------------------------------------------------
// Wave-per-row softmax + top-k + renormalize + store. No __syncthreads.
// lv[j] = relu'd, temperature-scaled logits at positions m = lane + 64*j.
// Tie-break: max value, lowest index (matches lax.top_k stability).
// ---------------------------------------------------------------------------
__device__ __forceinline__ void wave_softmax_topk_store(
    float lv[RPW_], int lane, float* __restrict__ outrow)
{
    float mx = 0.f;                     // logits >= 0 (post-relu), 0 is a valid floor
    #pragma unroll
    for (int j=0;j<RPW_;++j) mx = fmaxf(mx, lv[j]);
    #pragma unroll
    for (int s=1;s<64;s<<=1) mx = fmaxf(mx, __shfl_xor(mx, s));
    float sm = 0.f;
    #pragma unroll
    for (int j=0;j<RPW_;++j) {
        const int m = lane + 64*j;
        const float e = (m < N_) ? expf(lv[j]-mx) : 0.f;
        lv[j] = e; sm += e;
    }
    #pragma unroll
    for (int s=1;s<64;s<<=1) sm += __shfl_xor(sm, s);
    const float inv = 1.0f/sm;
    #pragma unroll
    for (int j=0;j<RPW_;++j) lv[j] *= inv;

    unsigned sel = 0u;
    float ksum = 0.f;
    for (int it = 0; it < K_; ++it) {
        float bv = -1.f; int bm = 0x7fffffff;
        #pragma unroll
        for (int j=0;j<RPW_;++j) {
            const int m = lane + 64*j;
            if (m < N_ && !((sel>>j)&1u) && lv[j] > bv) { bv = lv[j]; bm = m; }
        }
        #pragma unroll
        for (int s=1;s<64;s<<=1) {
            const float ov = __shfl_xor(bv, s);
            const int   om = __shfl_xor(bm, s);
            if (ov > bv || (ov == bv && om < bm)) { bv = ov; bm = om; }
        }
        ksum += bv;
        if ((bm & 63) == lane) sel |= 1u << (bm >> 6);
    }
    const float dn = 1.0f/(ksum + 1e-8f);
    #pragma unroll
    for (int j=0;j<RPW_;++j) {
        const int m = lane + 64*j;
        if (m < N_) outrow[m] = ((sel>>j)&1u) ? lv[j]*dn : 0.f;
    }
}

// ---------------------------------------------------------------------------
// Kernel 5: static adjacency — one WAVE per (h,n) row; 4 rows per block
// ---------------------------------------------------------------------------
__global__ __launch_bounds__(256) void static_adj_kernel(
    const float* __restrict__ le1, const float* __restrict__ le2,
    const float* __restrict__ ge1, const float* __restrict__ ge2,
    const float* __restrict__ temp, float* __restrict__ outs)
{
    __shared__ float e1l[4][ND_];
    const int tid = threadIdx.x;
    const int wv = tid >> 6, lane = tid & 63;
    const int r = blockIdx.x*4 + wv;        // r = h*N_ + n, grid = H_*N_/4
    const int h = r / N_, n = r % N_;
    if (h < 2) { if (lane < 32) e1l[wv][lane] = le1[(h*N_+n)*32+lane]; }
    else       { e1l[wv][lane] = ge1[((h-2)*N_+n)*64+lane]; }
    __syncthreads();
    const float t = temp[h];
    const float tl = (h < 2) ? fminf(fmaxf(t*2.0f,0.1f),5.0f) : fminf(fmaxf(t*0.5f,0.1f),2.0f);
    const float invt = 1.0f/tl;
    float lv[RPW_];
    #pragma unroll
    for (int j=0;j<RPW_;++j) lv[j] = 0.f;
    if (h < 2) {
        for (int c = 0; c < 32; ++c) {
            const float dc = e1l[wv][c];
            const float* sr = le2 + (size_t)(h*32+c)*N_;
            #pragma unroll
            for (int j=0;j<RPW_;++j) {
                const int m = lane + 64*j;
                if (m < N_) lv[j] += dc*sr[m];
            }
        }
    } else {
        for (int c = 0; c < 64; ++c) {
            const float dc = e1l[wv][c];
            const float* sr = ge2 + (size_t)((h-2)*64+c)*N_;
            #pragma unroll
            for (int j=0;j<RPW_;++j) {
                const int m = lane + 64*j;
                if (m < N_) lv[j] += dc*sr[m];
            }
        }
    }
    #pragma unroll
    for (int j=0;j<RPW_;++j) lv[j] = fmaxf(lv[j],0.f)*invt;
    wave_softmax_topk_store(lv, lane, outs + (size_t)r*N_);
}

// ---------------------------------------------------------------------------
// Kernel 6: dynamic adjacency — one WAVE per (b,h,n) row; 4 rows per block
// ---------------------------------------------------------------------------
__global__ __launch_bounds__(256) void dyn_adj_kernel(
    const float* __restrict__ dyn, const float* __restrict__ se2,
    const float* __restrict__ temp, float* __restrict__ outd)
{
    __shared__ float dql[4][ND_];
    const int tid = threadIdx.x;
    const int wv = tid >> 6, lane = tid & 63;
    const int r = blockIdx.x*4 + wv;        // grid = B_*H_*N_/4 = 5728
    const int b = r / (H_*N_);
    const int rem = r % (H_*N_);
    const int h = rem / N_, n = rem % N_;
    dql[wv][lane] = dyn[((size_t)(b*N_+n))*ND_ + lane];
    __syncthreads();
    const float invt = 1.0f/fminf(fmaxf(temp[h],0.1f),2.0f);
    float lv[RPW_];
    #pragma unroll
    for (int j=0;j<RPW_;++j) lv[j] = 0.f;
    const float* sb = se2 + (size_t)h*ND_*N_;
    for (int c = 0; c < ND_; ++c) {
        const float dc = dql[wv][c];
        const float* sr = sb + (size_t)c*N_;
        #pragma unroll
        for (int j=0;j<RPW_;++j) {
            const int m = lane + 64*j;
            if (m < N_) lv[j] += dc*sr[m];
        }
    }
    #pragma unroll
    for (int j=0;j<RPW_;++j) lv[j] = fmaxf(lv[j],0.f)*invt;
    wave_softmax_topk_store(lv, lane, outd + ((size_t)(b*H_+h)*N_+n)*(size_t)N_);
}

// ---------------------------------------------------------------------------
// Kernel 7: fusion gate  w = sigmoid(node_f @ gf_w + gf_b)
// ---------------------------------------------------------------------------
__global__ __launch_bounds__(256) void fw_kernel(
    const float* __restrict__ meanpr, const float* __restrict__ gfw,
    const float* __restrict__ gfb, float* __restrict__ wf)
{
    const int gid = blockIdx.x*256 + threadIdx.x;
    if (gid >= BN_*H_) return;
    const int bn = gid >> 2, h = gid & 3;
    float s = gfb[h];
    const float* mp = meanpr + (size_t)bn*D_;
    for (int c=0;c<D_;++c) s += mp[c]*gfw[c*H_+h];
    wf[gid] = sigm_f(s);
}

// ---------------------------------------------------------------------------
// Kernel 8: fusion + edge-encoder MLP + final (one thread per (b,n,m))
// ---------------------------------------------------------------------------
__global__ __launch_bounds__(256) void edge_kernel(
    const float* __restrict__ staticf, const float* __restrict__ dynf,
    const float* __restrict__ wf,
    const float* __restrict__ ew1, const float* __restrict__ eb1,
    const float* __restrict__ eg,  const float* __restrict__ ebe,
    const float* __restrict__ ew2, const float* __restrict__ eb2,
    const float* __restrict__ ew3, const float* __restrict__ eb3,
    float* __restrict__ outf)
{
    __shared__ float w1s[64], w2s[128], b1s[16], gs[16], bes[16], b2s[8], w3s[8];
    __shared__ float b3v;
    const int tid = threadIdx.x;
    if (tid < 64)                 w1s[tid]     = ew1[tid];
    else if (tid < 192)           w2s[tid-64]  = ew2[tid-64];
    else if (tid < 208)           b1s[tid-192] = eb1[tid-192];
    else if (tid < 224)           gs[tid-208]  = eg[tid-208];
    else if (tid < 240)           bes[tid-224] = ebe[tid-224];
    else if (tid < 248)           b2s[tid-240] = eb2[tid-240];
    else                          w3s[tid-248] = ew3[tid-248];
    if (tid == 0) b3v = eb3[0];
    __syncthreads();

    const size_t gid = (size_t)blockIdx.x*256 + tid;
    if (gid >= (size_t)B_*NN_) return;
    const int m = (int)(gid % N_);
    const size_t t1 = gid / N_;
    const int n = (int)(t1 % N_);
    const int b = (int)(t1 / N_);

    const float* wrow = wf + ((size_t)(b*N_+n))*4;
    float mh[4]; float msum = 0.f;
    #pragma unroll
    for (int h=0; h<4; ++h) {
        float w  = wrow[h];
        float st = staticf[((size_t)(h*N_+n))*N_ + m];
        float da = dynf[(((size_t)(b*4+h))*N_+n)*(size_t)N_ + m];
        float f = (1.0f-w)*st + w*da;
        mh[h] = f; msum += f;
    }
    float e16[16]; float mean = 0.f;
    #pragma unroll
    for (int j=0;j<16;++j) {
        float s = b1s[j];
        #pragma unroll
        for (int h=0;h<4;++h) s += mh[h]*w1s[h*16+j];
        e16[j] = s; mean += s;
    }
    mean *= (1.0f/16.0f);
    float var = 0.f;
    #pragma unroll
    for (int j=0;j<16;++j){ float df=e16[j]-mean; var += df*df; }
    var *= (1.0f/16.0f);
    const float rinv = rsqrtf(var + 1e-5f);
    #pragma unroll
    for (int j=0;j<16;++j) e16[j] = gelu_f((e16[j]-mean)*rinv*gs[j] + bes[j]);
    float e8[8];
    #pragma unroll
    for (int o=0;o<8;++o) {
        float s = b2s[o];
        #pragma unroll
        for (int j=0;j<16;++j) s += e16[j]*w2s[j*8+o];
        e8[o] = gelu_f(s);
    }
    float e = b3v;
    #pragma unroll
    for (int o=0;o<8;++o) e += e8[o]*w3s[o];
    outf[gid] = sigm_f(e) * (msum*0.25f);
}

// ---------------------------------------------------------------------------
extern "C" void kernel_launch(void* const* d_in, const int* in_sizes, int n_in,
                              void* d_out, int out_size, void* d_ws, size_t ws_size,
                              hipStream_t stream)
{
    const float* patch = (const float*)d_in[0];
    const float* le1   = (const float*)d_in[1];
    const float* le2   = (const float*)d_in[2];
    const float* ge1   = (const float*)d_in[3];
    const float* ge2   = (const float*)d_in[4];
    const float* se2   = (const float*)d_in[5];
    const float* temp  = (const float*)d_in[6];
    const float* pos   = (const float*)d_in[7];
    const float* wq    = (const float*)d_in[8];
    const float* bq    = (const float*)d_in[9];
    const float* wk    = (const float*)d_in[10];
    const float* bk    = (const float*)d_in[11];
    const float* wv    = (const float*)d_in[12];
    const float* bv    = (const float*)d_in[13];
    const float* wo    = (const float*)d_in[14];
    const float* bo    = (const float*)d_in[15];
    const float* tng   = (const float*)d_in[16];
    const float* tnb   = (const float*)d_in[17];
    const float* dw1   = (const float*)d_in[18];
    const float* db1   = (const float*)d_in[19];
    const float* dg1   = (const float*)d_in[20];
    const float* dbe1  = (const float*)d_in[21];
    const float* dw2   = (const float*)d_in[22];
    const float* db2   = (const float*)d_in[23];
    const float* dg2   = (const float*)d_in[24];
    const float* dbe2  = (const float*)d_in[25];
    const float* gw    = (const float*)d_in[26];
    const float* gb    = (const float*)d_in[27];
    const float* gg    = (const float*)d_in[28];
    const float* gbe   = (const float*)d_in[29];
    const float* gfw   = (const float*)d_in[30];
    const float* gfb   = (const float*)d_in[31];
    const float* ew1   = (const float*)d_in[32];
    const float* eb1   = (const float*)d_in[33];
    const float* eg    = (const float*)d_in[34];
    const float* ebe   = (const float*)d_in[35];
    const float* ew2   = (const float*)d_in[36];
    const float* eb2   = (const float*)d_in[37];
    const float* ew3   = (const float*)d_in[38];
    const float* eb3   = (const float*)d_in[39];
    (void)in_sizes; (void)n_in; (void)out_size; (void)ws_size;

    // workspace layout (with aliasing of dead buffers): BN*384 floats = 8.8 MB
    float* ws      = (float*)d_ws;
    float* meanpr  = ws;                        // BN*96, live until fw_kernel
    float* node    = meanpr + (size_t)BN_*D_;   // BN*96; dead after enc1 -> reused as dyn1
    float* h1      = node   + (size_t)BN_*D_;   // BN*128; dead after enc2 -> reused as wfuse
    float* dyn0    = h1     + (size_t)BN_*128;  // BN*64
    float* dyn1    = node;                      // alias (gnn layer0 output)
    float* wfuse   = h1;                        // alias (BN*4)

    float* out        = (float*)d_out;
    float* out_final  = out;
    float* out_static = out + (size_t)B_*NN_;
    float* out_dyn    = out_static + (size_t)H_*NN_;

    attn_kernel<<<BN_, 256, 0, stream>>>(patch,pos,wq,bq,wk,bk,wv,bv,wo,bo,tng,tnb,node,meanpr);
    enc1_kernel<<<BN_, 128, 0, stream>>>(node,dw1,db1,dg1,dbe1,h1);
    enc2_kernel<<<BN_, 64,  0, stream>>>(h1,dw2,db2,dg2,dbe2,dyn0);
    gnn_kernel<<<BN_, 256, 0, stream>>>(dyn0,dyn1,gw,gb,gg,gbe,0);
    gnn_kernel<<<BN_, 256, 0, stream>>>(dyn1,dyn0,gw,gb,gg,gbe,1);
    static_adj_kernel<<<H_*N_/4, 256, 0, stream>>>(le1,le2,ge1,ge2,temp,out_static);
    dyn_adj_kernel<<<B_*H_*N_/4, 256, 0, stream>>>(dyn0,se2,temp,out_dyn);
    fw_kernel<<<(BN_*H_+255)/256, 256, 0, stream>>>(meanpr,gfw,gfb,wfuse);
    edge_kernel<<<((size_t)B_*NN_+255)/256, 256, 0, stream>>>(
        out_static,out_dyn,wfuse,ew1,eb1,eg,ebe,ew2,eb2,ew3,eb3,out_final);
}